// Round 5
// baseline (373.789 us; speedup 1.0000x reference)
//
#include <hip/hip_runtime.h>
#include <math.h>

// Problem constants (B=8, S=2048, D=512)
#define B_ 8
#define S_ 2048
#define D_ 512
#define KTOP 204                      // int(2048*0.1)
#define QK_SCALE 0.044194173824159216f // 1/sqrt(512)

typedef short bfrag8 __attribute__((ext_vector_type(8)));  // 8 bf16 (4 VGPRs)
typedef float facc4 __attribute__((ext_vector_type(4)));   // MFMA accumulator

// ---------- helpers ----------
__device__ __forceinline__ unsigned short f2bf(float f) {
  unsigned u = __float_as_uint(f);
  u += 0x7FFFu + ((u >> 16) & 1);   // RNE
  return (unsigned short)(u >> 16);
}

// order-preserving map: descending float order == descending uint order
__device__ __forceinline__ unsigned fkey(float f) {
  unsigned b = __float_as_uint(f);
  return (b & 0x80000000u) ? ~b : (b | 0x80000000u);
}
__device__ __forceinline__ float keyfloat(unsigned k) {
  unsigned b = (k & 0x80000000u) ? (k & 0x7FFFFFFFu) : ~k;
  return __uint_as_float(b);
}

__device__ __forceinline__ void load16(const unsigned short* g, unsigned short* l) {
  __builtin_amdgcn_global_load_lds(
      (const __attribute__((address_space(1))) void*)g,
      (__attribute__((address_space(3))) void*)l, 16, 0, 0);
}

// ---------- fp32 -> bf16 convert, Q and K in one launch ----------
__global__ __launch_bounds__(256) void cvt_qk(const float* __restrict__ Q,
                                              const float* __restrict__ K,
                                              unsigned short* __restrict__ Qb,
                                              unsigned short* __restrict__ Kb) {
  const float* in = blockIdx.y ? K : Q;
  unsigned short* out = blockIdx.y ? Kb : Qb;
  int i = (blockIdx.x * 256 + threadIdx.x) * 4;
  float4 v = *(const float4*)(in + i);
  ushort4 o;
  o.x = f2bf(v.x); o.y = f2bf(v.y); o.z = f2bf(v.z); o.w = f2bf(v.w);
  *(ushort4*)(out + i) = o;
}

// ---------- V [b][k][d] fp32 -> VT [b][d][k] bf16 ----------
__global__ __launch_bounds__(256) void transpose_v(const float* __restrict__ V,
                                                   unsigned short* __restrict__ VT) {
  __shared__ float tile[32][33];
  int b = blockIdx.z;
  int d0 = blockIdx.x * 32, k0 = blockIdx.y * 32;
  const float* Vb = V + (size_t)b * S_ * D_;
  unsigned short* VTb = VT + (size_t)b * D_ * S_;
  int c = threadIdx.x & 31, r = threadIdx.x >> 5;
#pragma unroll
  for (int rr = 0; rr < 32; rr += 8)
    tile[r + rr][c] = Vb[(size_t)(k0 + r + rr) * D_ + d0 + c];
  __syncthreads();
#pragma unroll
  for (int rr = 0; rr < 32; rr += 8)
    VTb[(size_t)(d0 + r + rr) * S_ + k0 + c] = f2bf(tile[c][r + rr]);
}

// ---------- batched BT-layout MFMA GEMM: C[m][n] = scale * sum_k A[m][k]*Bm[n][k] ----------
// 128x128 tile, BK=32, 4 waves, 4x4 16x16x32 MFMAs per wave, async global->LDS staging.
// (verbatim Round-2 kernel)
__global__ __launch_bounds__(256) void gemm_bt(
    const unsigned short* __restrict__ A, int lda, long long astr,
    const unsigned short* __restrict__ Bm, int ldb, long long bstr,
    float* __restrict__ C, int ldc, long long cstr,
    int kdim, float scale) {
  __shared__ unsigned short smA[128 * 32];
  __shared__ unsigned short smB[128 * 32];
  const int tid = threadIdx.x;
  const int wave = tid >> 6, lane = tid & 63;
  const int quad = lane >> 4, l15 = lane & 15;
  const unsigned short* Ab = A + (long long)blockIdx.z * astr + (size_t)(blockIdx.y * 128) * lda;
  const unsigned short* Bb = Bm + (long long)blockIdx.z * bstr + (size_t)(blockIdx.x * 128) * ldb;
  const int srow = tid >> 2;          // staging row 0..63
  const int scol = (tid & 3) * 8;     // staging col (elements)
  unsigned short* lA0 = smA + wave * 512;
  unsigned short* lA1 = smA + 2048 + wave * 512;
  unsigned short* lB0 = smB + wave * 512;
  unsigned short* lB1 = smB + 2048 + wave * 512;
  const int mrow = 64 * (wave >> 1);
  const int nrow = 64 * (wave & 1);

  facc4 acc[4][4];
  const facc4 fzero = {0.f, 0.f, 0.f, 0.f};
#pragma unroll
  for (int i = 0; i < 4; ++i)
#pragma unroll
    for (int j = 0; j < 4; ++j) acc[i][j] = fzero;

  for (int k0 = 0; k0 < kdim; k0 += 32) {
    __syncthreads();
    load16(Ab + (size_t)srow * lda + k0 + scol, lA0);
    load16(Ab + (size_t)(srow + 64) * lda + k0 + scol, lA1);
    load16(Bb + (size_t)srow * ldb + k0 + scol, lB0);
    load16(Bb + (size_t)(srow + 64) * ldb + k0 + scol, lB1);
    __syncthreads();
    bfrag8 af[4], bq[4];
#pragma unroll
    for (int i = 0; i < 4; ++i)
      af[i] = *(const bfrag8*)(smA + (mrow + 16 * i + l15) * 32 + quad * 8);
#pragma unroll
    for (int j = 0; j < 4; ++j)
      bq[j] = *(const bfrag8*)(smB + (nrow + 16 * j + l15) * 32 + quad * 8);
#pragma unroll
    for (int i = 0; i < 4; ++i)
#pragma unroll
      for (int j = 0; j < 4; ++j)
        acc[i][j] = __builtin_amdgcn_mfma_f32_16x16x32_bf16(af[i], bq[j], acc[i][j], 0, 0, 0);
  }

  float* Cb = C + (long long)blockIdx.z * cstr;
  const int mg = blockIdx.y * 128 + mrow;
  const int ng = blockIdx.x * 128 + nrow;
#pragma unroll
  for (int i = 0; i < 4; ++i)
#pragma unroll
    for (int j = 0; j < 4; ++j)
#pragma unroll
      for (int r = 0; r < 4; ++r)
        Cb[(size_t)(mg + 16 * i + quad * 4 + r) * ldc + ng + 16 * j + l15] = acc[i][j][r] * scale;
}

// ---------- 128x64-tile variant (wave tile 64x32, acc 4x2) — gemm2 only ----------
__global__ __launch_bounds__(256) void gemm_bt2(
    const unsigned short* __restrict__ A, int lda, long long astr,
    const unsigned short* __restrict__ Bm, int ldb, long long bstr,
    float* __restrict__ C, int ldc, long long cstr,
    int kdim, float scale) {
  __shared__ unsigned short smA[128 * 32];
  __shared__ unsigned short smB[64 * 32];
  const int tid = threadIdx.x;
  const int wave = tid >> 6, lane = tid & 63;
  const int quad = lane >> 4, l15 = lane & 15;
  const unsigned short* Ab = A + (long long)blockIdx.z * astr + (size_t)(blockIdx.y * 128) * lda;
  const unsigned short* Bb = Bm + (long long)blockIdx.z * bstr + (size_t)(blockIdx.x * 64) * ldb;
  const int srow = tid >> 2;          // staging row 0..63
  const int scol = (tid & 3) * 8;     // staging col (elements)
  unsigned short* lA0 = smA + wave * 512;
  unsigned short* lA1 = smA + 2048 + wave * 512;
  unsigned short* lB0 = smB + wave * 512;
  const int mrow = 64 * (wave >> 1);
  const int nrow = 32 * (wave & 1);

  facc4 acc[4][2];
  const facc4 fzero = {0.f, 0.f, 0.f, 0.f};
#pragma unroll
  for (int i = 0; i < 4; ++i)
#pragma unroll
    for (int j = 0; j < 2; ++j) acc[i][j] = fzero;

  for (int k0 = 0; k0 < kdim; k0 += 32) {
    __syncthreads();
    load16(Ab + (size_t)srow * lda + k0 + scol, lA0);
    load16(Ab + (size_t)(srow + 64) * lda + k0 + scol, lA1);
    load16(Bb + (size_t)srow * ldb + k0 + scol, lB0);
    __syncthreads();
    bfrag8 af[4], bq[2];
#pragma unroll
    for (int i = 0; i < 4; ++i)
      af[i] = *(const bfrag8*)(smA + (mrow + 16 * i + l15) * 32 + quad * 8);
#pragma unroll
    for (int j = 0; j < 2; ++j)
      bq[j] = *(const bfrag8*)(smB + (nrow + 16 * j + l15) * 32 + quad * 8);
#pragma unroll
    for (int i = 0; i < 4; ++i)
#pragma unroll
      for (int j = 0; j < 2; ++j)
        acc[i][j] = __builtin_amdgcn_mfma_f32_16x16x32_bf16(af[i], bq[j], acc[i][j], 0, 0, 0);
  }

  float* Cb = C + (long long)blockIdx.z * cstr;
  const int mg = blockIdx.y * 128 + mrow;
  const int ng = blockIdx.x * 64 + nrow;
#pragma unroll
  for (int i = 0; i < 4; ++i)
#pragma unroll
    for (int j = 0; j < 2; ++j)
#pragma unroll
      for (int r = 0; r < 4; ++r)
        Cb[(size_t)(mg + 16 * i + quad * 4 + r) * ldc + ng + 16 * j + l15] = acc[i][j][r] * scale;
}

// ---------- per-row exact top-204 + softmax-of-sparse; one WAVE per row ----------
// (verbatim Round-2 kernel)
// 64 lanes x 32 register-resident keys; wave-private 256-bin LDS histogram;
// all scans/reductions via shuffles — zero __syncthreads.
// Element i (0..31) of lane L has global index (i>>3)*512 + L*8 + (i&7).
__global__ __launch_bounds__(256) void topk_softmax(float* __restrict__ scores) {
  __shared__ unsigned binsAll[4][256];
  const int tid = threadIdx.x;
  const int wave = tid >> 6, lane = tid & 63;
  const long long row = (long long)blockIdx.x * 4 + wave;
  float* srow = scores + row * 2048;
  unsigned* bins = binsAll[wave];

  unsigned k[32];
#pragma unroll
  for (int c = 0; c < 4; ++c) {
    float4 a = *(const float4*)(srow + c * 512 + lane * 8);
    float4 b = *(const float4*)(srow + c * 512 + lane * 8 + 4);
    k[c * 8 + 0] = fkey(a.x); k[c * 8 + 1] = fkey(a.y);
    k[c * 8 + 2] = fkey(a.z); k[c * 8 + 3] = fkey(a.w);
    k[c * 8 + 4] = fkey(b.x); k[c * 8 + 5] = fkey(b.y);
    k[c * 8 + 6] = fkey(b.z); k[c * 8 + 7] = fkey(b.w);
  }

  // row max (for softmax shift m = max(max_score, 0))
  unsigned kmax = 0;
#pragma unroll
  for (int i = 0; i < 32; ++i) kmax = max(kmax, k[i]);
#pragma unroll
  for (int off = 1; off < 64; off <<= 1)
    kmax = max(kmax, (unsigned)__shfl_xor((int)kmax, off));
  const float m = fmaxf(keyfloat(kmax), 0.f);

  // 4-pass radix select (MSB->LSB) for the KTOP-th largest key
  unsigned prefix = 0, mmask = 0, krem = KTOP;
  for (int shift = 24; shift >= 0; shift -= 8) {
    uint4 z; z.x = z.y = z.z = z.w = 0;
    *(uint4*)(bins + lane * 4) = z;
#pragma unroll
    for (int i = 0; i < 32; ++i)
      if ((k[i] & mmask) == prefix) atomicAdd(&bins[(k[i] >> shift) & 255], 1u);
    uint4 b = *(const uint4*)(bins + lane * 4);
    unsigned s = b.x + b.y + b.z + b.w;
    // inclusive suffix scan of s over lanes (sum over lanes >= this lane)
    unsigned t = s;
#pragma unroll
    for (int off = 1; off < 64; off <<= 1) {
      unsigned u = (unsigned)__shfl_down((int)t, off);
      t += (lane + off < 64) ? u : 0u;
    }
    const unsigned texcl = t - s;           // suffix over lanes > lane
    const unsigned c3 = texcl + b.w;        // count(digit >= lane*4+3)
    const unsigned c2 = c3 + b.z;
    const unsigned c1 = c2 + b.y;
    const unsigned c0 = c1 + b.x;
    unsigned pack = 0;                      // nonzero in exactly one lane
    if (c0 >= krem && c1 < krem)   pack = ((krem - c1) << 8) | (lane * 4 + 0);
    if (c1 >= krem && c2 < krem)   pack = ((krem - c2) << 8) | (lane * 4 + 1);
    if (c2 >= krem && c3 < krem)   pack = ((krem - c3) << 8) | (lane * 4 + 2);
    if (c3 >= krem && texcl < krem) pack = ((krem - texcl) << 8) | (lane * 4 + 3);
#pragma unroll
    for (int off = 1; off < 64; off <<= 1)
      pack |= (unsigned)__shfl_xor((int)pack, off);
    prefix |= (pack & 255u) << shift;
    krem = pack >> 8;                       // >=1 by construction
    mmask |= 0xFFu << shift;
  }
  const unsigned tkey = prefix;

  // tie-break: accept the krem lowest-index elements with key == tkey.
  // cut = global index of the last accepted tie.
  unsigned cut;
  {
    unsigned tiem = 0;
#pragma unroll
    for (int i = 0; i < 32; ++i)
      if (k[i] == tkey) tiem |= 1u << i;
    unsigned need = krem;
    for (;;) {
      unsigned myidx = 0xFFFFFFFFu;
      if (tiem) {
        int i = __ffs((int)tiem) - 1;       // lowest i = smallest global idx in lane
        myidx = ((unsigned)(i >> 3)) * 512u + (unsigned)lane * 8u + (unsigned)(i & 7);
      }
      unsigned minidx = myidx;
#pragma unroll
      for (int off = 1; off < 64; off <<= 1)
        minidx = min(minidx, (unsigned)__shfl_xor((int)minidx, off));
      if (--need == 0 || minidx == 0xFFFFFFFFu) { cut = minidx; break; }
      if (myidx == minidx) tiem &= tiem - 1; // consume in owning lane
    }
  }

  // weights: exp(s-m) if selected, exp(-m) otherwise; Z = sum of all weights
  const float eqw = __expf(keyfloat(tkey) - m);
  const float base = __expf(-m);
  float zsum = 0.f;
#pragma unroll
  for (int i = 0; i < 32; ++i) {
    const unsigned key = k[i];
    const unsigned idx = ((unsigned)(i >> 3)) * 512u + (unsigned)lane * 8u + (unsigned)(i & 7);
    float w;
    if (key > tkey) w = __expf(keyfloat(key) - m);
    else w = (key == tkey && idx <= cut) ? eqw : base;
    zsum += w;
    k[i] = __float_as_uint(w);              // stash unnormalized weight
  }
#pragma unroll
  for (int off = 1; off < 64; off <<= 1) zsum += __shfl_xor(zsum, off);
  const float invZ = 1.f / zsum;

  // attn row (bf16) reuses the front 4KB of this row's 8KB score slot
  unsigned short* arow = (unsigned short*)scores + row * 4096;
#pragma unroll
  for (int c = 0; c < 4; ++c) {
    union { unsigned short u[8]; int4 v4; } pk;
#pragma unroll
    for (int j = 0; j < 8; ++j)
      pk.u[j] = f2bf(__uint_as_float(k[c * 8 + j]) * invZ);
    *(int4*)(arow + c * 512 + lane * 8) = pk.v4;
  }
}

// ---------- launch ----------
// ws layout (bytes): Qb[0,16MB) Kb[16,32MB) VT[32,48MB) scores/attn[48,176MB)
extern "C" void kernel_launch(void* const* d_in, const int* in_sizes, int n_in,
                              void* d_out, int out_size, void* d_ws, size_t ws_size,
                              hipStream_t stream) {
  const float* Q = (const float*)d_in[0];
  const float* K = (const float*)d_in[1];
  const float* V = (const float*)d_in[2];
  float* out = (float*)d_out;
  char* ws = (char*)d_ws;
  unsigned short* Qb = (unsigned short*)(ws);
  unsigned short* Kb = (unsigned short*)(ws + ((size_t)16 << 20));
  unsigned short* VT = (unsigned short*)(ws + ((size_t)32 << 20));
  float* scores = (float*)(ws + ((size_t)48 << 20));

  const int nel = B_ * S_ * D_;  // 8388608
  cvt_qk<<<dim3(nel / 1024, 2), 256, 0, stream>>>(Q, K, Qb, Kb);
  transpose_v<<<dim3(D_ / 32, S_ / 32, B_), 256, 0, stream>>>(V, VT);
  // scores[b][q][k] = sum_d Q[q][d]*K[k][d] * scale ; score row pitch = 2048 f32
  gemm_bt<<<dim3(S_ / 128, S_ / 128, B_), 256, 0, stream>>>(
      Qb, D_, (long long)S_ * D_, Kb, D_, (long long)S_ * D_,
      scores, S_, (long long)S_ * S_, D_, QK_SCALE);
  topk_softmax<<<B_ * S_ / 4, 256, 0, stream>>>(scores);
  // out[b][q][d] = sum_k attn[q][k]*VT[d][k] ; attn row pitch = 4096 bf16 (8KB slots)
  gemm_bt2<<<dim3(D_ / 64, S_ / 128, B_), 256, 0, stream>>>(
      (const unsigned short*)scores, 4096, (long long)S_ * 4096,
      VT, S_, (long long)D_ * S_, out, D_, (long long)S_ * D_, S_, 1.0f);
}

// Round 6
// 319.020 us; speedup vs baseline: 1.1717x; 1.1717x over previous
//
#include <hip/hip_runtime.h>
#include <math.h>

// Problem constants (B=8, S=2048, D=512)
#define B_ 8
#define S_ 2048
#define D_ 512
#define KTOP 204                      // int(2048*0.1)
#define QK_SCALE 0.044194173824159216f // 1/sqrt(512)

typedef short bfrag8 __attribute__((ext_vector_type(8)));  // 8 bf16 (4 VGPRs)
typedef float facc4 __attribute__((ext_vector_type(4)));   // MFMA accumulator

// ---------- helpers ----------
__device__ __forceinline__ unsigned short f2bf(float f) {
  unsigned u = __float_as_uint(f);
  u += 0x7FFFu + ((u >> 16) & 1);   // RNE
  return (unsigned short)(u >> 16);
}

// order-preserving map: descending float order == descending uint order
__device__ __forceinline__ unsigned fkey(float f) {
  unsigned b = __float_as_uint(f);
  return (b & 0x80000000u) ? ~b : (b | 0x80000000u);
}
__device__ __forceinline__ float keyfloat(unsigned k) {
  unsigned b = (k & 0x80000000u) ? (k & 0x7FFFFFFFu) : ~k;
  return __uint_as_float(b);
}

__device__ __forceinline__ void load16(const unsigned short* g, unsigned short* l) {
  __builtin_amdgcn_global_load_lds(
      (const __attribute__((address_space(1))) void*)g,
      (__attribute__((address_space(3))) void*)l, 16, 0, 0);
}

// ---------- fp32 -> bf16 convert, Q and K in one launch ----------
__global__ __launch_bounds__(256) void cvt_qk(const float* __restrict__ Q,
                                              const float* __restrict__ K,
                                              unsigned short* __restrict__ Qb,
                                              unsigned short* __restrict__ Kb) {
  const float* in = blockIdx.y ? K : Q;
  unsigned short* out = blockIdx.y ? Kb : Qb;
  int i = (blockIdx.x * 256 + threadIdx.x) * 4;
  float4 v = *(const float4*)(in + i);
  ushort4 o;
  o.x = f2bf(v.x); o.y = f2bf(v.y); o.z = f2bf(v.z); o.w = f2bf(v.w);
  *(ushort4*)(out + i) = o;
}

// ---------- V [b][k][d] fp32 -> VT [b][d][k] bf16 ----------
__global__ __launch_bounds__(256) void transpose_v(const float* __restrict__ V,
                                                   unsigned short* __restrict__ VT) {
  __shared__ float tile[32][33];
  int b = blockIdx.z;
  int d0 = blockIdx.x * 32, k0 = blockIdx.y * 32;
  const float* Vb = V + (size_t)b * S_ * D_;
  unsigned short* VTb = VT + (size_t)b * D_ * S_;
  int c = threadIdx.x & 31, r = threadIdx.x >> 5;
#pragma unroll
  for (int rr = 0; rr < 32; rr += 8)
    tile[r + rr][c] = Vb[(size_t)(k0 + r + rr) * D_ + d0 + c];
  __syncthreads();
#pragma unroll
  for (int rr = 0; rr < 32; rr += 8)
    VTb[(size_t)(d0 + r + rr) * S_ + k0 + c] = f2bf(tile[c][r + rr]);
}

// ---------- batched BT-layout MFMA GEMM: C[m][n] = scale * sum_k A[m][k]*Bm[n][k] ----------
// 128x128 tile, BK=32, 4 waves, 4x4 16x16x32 MFMAs per wave (verbatim R2 body).
// gemm1 variant: grid (16,16,8); XCD swizzle — bz = j&7 so each batch pins to one
// XCD (Qb[b]+Kb[b] = 4 MB = one XCD L2); within XCD, by fastest.
__global__ __launch_bounds__(256) void gemm_qk(
    const unsigned short* __restrict__ A, int lda, long long astr,
    const unsigned short* __restrict__ Bm, int ldb, long long bstr,
    float* __restrict__ C, int ldc, long long cstr,
    int kdim, float scale) {
  const unsigned j = blockIdx.x + 16u * blockIdx.y + 256u * blockIdx.z;
  const unsigned bz = j & 7u;           // batch == XCD residue
  const unsigned q = j >> 3;            // [0,256)
  const unsigned by = q & 15u;          // m-tile
  const unsigned bx = q >> 4;           // n-tile [0,16)

  __shared__ unsigned short smA[128 * 32];
  __shared__ unsigned short smB[128 * 32];
  const int tid = threadIdx.x;
  const int wave = tid >> 6, lane = tid & 63;
  const int quad = lane >> 4, l15 = lane & 15;
  const unsigned short* Ab = A + (long long)bz * astr + (size_t)(by * 128) * lda;
  const unsigned short* Bb = Bm + (long long)bz * bstr + (size_t)(bx * 128) * ldb;
  const int srow = tid >> 2;          // staging row 0..63
  const int scol = (tid & 3) * 8;     // staging col (elements)
  unsigned short* lA0 = smA + wave * 512;
  unsigned short* lA1 = smA + 2048 + wave * 512;
  unsigned short* lB0 = smB + wave * 512;
  unsigned short* lB1 = smB + 2048 + wave * 512;
  const int mrow = 64 * (wave >> 1);
  const int nrow = 64 * (wave & 1);

  facc4 acc[4][4];
  const facc4 fzero = {0.f, 0.f, 0.f, 0.f};
#pragma unroll
  for (int i = 0; i < 4; ++i)
#pragma unroll
    for (int j2 = 0; j2 < 4; ++j2) acc[i][j2] = fzero;

  for (int k0 = 0; k0 < kdim; k0 += 32) {
    __syncthreads();
    load16(Ab + (size_t)srow * lda + k0 + scol, lA0);
    load16(Ab + (size_t)(srow + 64) * lda + k0 + scol, lA1);
    load16(Bb + (size_t)srow * ldb + k0 + scol, lB0);
    load16(Bb + (size_t)(srow + 64) * ldb + k0 + scol, lB1);
    __syncthreads();
    bfrag8 af[4], bq[4];
#pragma unroll
    for (int i = 0; i < 4; ++i)
      af[i] = *(const bfrag8*)(smA + (mrow + 16 * i + l15) * 32 + quad * 8);
#pragma unroll
    for (int j2 = 0; j2 < 4; ++j2)
      bq[j2] = *(const bfrag8*)(smB + (nrow + 16 * j2 + l15) * 32 + quad * 8);
#pragma unroll
    for (int i = 0; i < 4; ++i)
#pragma unroll
      for (int j2 = 0; j2 < 4; ++j2)
        acc[i][j2] = __builtin_amdgcn_mfma_f32_16x16x32_bf16(af[i], bq[j2], acc[i][j2], 0, 0, 0);
  }

  float* Cb = C + (long long)bz * cstr;
  const int mg = by * 128 + mrow;
  const int ng = bx * 128 + nrow;
#pragma unroll
  for (int i = 0; i < 4; ++i)
#pragma unroll
    for (int j2 = 0; j2 < 4; ++j2)
#pragma unroll
      for (int r = 0; r < 4; ++r)
        Cb[(size_t)(mg + 16 * i + quad * 4 + r) * ldc + ng + 16 * j2 + l15] = acc[i][j2][r] * scale;
}

// gemm2 variant: grid (4,16,8); bz = j&7 (batch pins to XCD, VT[b] 2 MB in L2);
// within XCD, bx fastest so the 4 n-blocks sharing one 512 KB attn A-tile run
// back-to-back on the same XCD (A fetched from HBM once).
__global__ __launch_bounds__(256) void gemm_pv(
    const unsigned short* __restrict__ A, int lda, long long astr,
    const unsigned short* __restrict__ Bm, int ldb, long long bstr,
    float* __restrict__ C, int ldc, long long cstr,
    int kdim, float scale) {
  const unsigned j = blockIdx.x + 4u * blockIdx.y + 64u * blockIdx.z;
  const unsigned bz = j & 7u;           // batch == XCD residue
  const unsigned q = j >> 3;            // [0,64)
  const unsigned bx = q & 3u;           // n-tile (fastest)
  const unsigned by = q >> 2;           // m-tile [0,16)

  __shared__ unsigned short smA[128 * 32];
  __shared__ unsigned short smB[128 * 32];
  const int tid = threadIdx.x;
  const int wave = tid >> 6, lane = tid & 63;
  const int quad = lane >> 4, l15 = lane & 15;
  const unsigned short* Ab = A + (long long)bz * astr + (size_t)(by * 128) * lda;
  const unsigned short* Bb = Bm + (long long)bz * bstr + (size_t)(bx * 128) * ldb;
  const int srow = tid >> 2;          // staging row 0..63
  const int scol = (tid & 3) * 8;     // staging col (elements)
  unsigned short* lA0 = smA + wave * 512;
  unsigned short* lA1 = smA + 2048 + wave * 512;
  unsigned short* lB0 = smB + wave * 512;
  unsigned short* lB1 = smB + 2048 + wave * 512;
  const int mrow = 64 * (wave >> 1);
  const int nrow = 64 * (wave & 1);

  facc4 acc[4][4];
  const facc4 fzero = {0.f, 0.f, 0.f, 0.f};
#pragma unroll
  for (int i = 0; i < 4; ++i)
#pragma unroll
    for (int j2 = 0; j2 < 4; ++j2) acc[i][j2] = fzero;

  for (int k0 = 0; k0 < kdim; k0 += 32) {
    __syncthreads();
    load16(Ab + (size_t)srow * lda + k0 + scol, lA0);
    load16(Ab + (size_t)(srow + 64) * lda + k0 + scol, lA1);
    load16(Bb + (size_t)srow * ldb + k0 + scol, lB0);
    load16(Bb + (size_t)(srow + 64) * ldb + k0 + scol, lB1);
    __syncthreads();
    bfrag8 af[4], bq[4];
#pragma unroll
    for (int i = 0; i < 4; ++i)
      af[i] = *(const bfrag8*)(smA + (mrow + 16 * i + l15) * 32 + quad * 8);
#pragma unroll
    for (int j2 = 0; j2 < 4; ++j2)
      bq[j2] = *(const bfrag8*)(smB + (nrow + 16 * j2 + l15) * 32 + quad * 8);
#pragma unroll
    for (int i = 0; i < 4; ++i)
#pragma unroll
      for (int j2 = 0; j2 < 4; ++j2)
        acc[i][j2] = __builtin_amdgcn_mfma_f32_16x16x32_bf16(af[i], bq[j2], acc[i][j2], 0, 0, 0);
  }

  float* Cb = C + (long long)bz * cstr;
  const int mg = by * 128 + mrow;
  const int ng = bx * 128 + nrow;
#pragma unroll
  for (int i = 0; i < 4; ++i)
#pragma unroll
    for (int j2 = 0; j2 < 4; ++j2)
#pragma unroll
      for (int r = 0; r < 4; ++r)
        Cb[(size_t)(mg + 16 * i + quad * 4 + r) * ldc + ng + 16 * j2 + l15] = acc[i][j2][r] * scale;
}

// ---------- per-row exact top-204 + softmax-of-sparse; one WAVE per row ----------
// (verbatim Round-2 kernel — proven passing; do not touch)
__global__ __launch_bounds__(256) void topk_softmax(float* __restrict__ scores) {
  __shared__ unsigned binsAll[4][256];
  const int tid = threadIdx.x;
  const int wave = tid >> 6, lane = tid & 63;
  const long long row = (long long)blockIdx.x * 4 + wave;
  float* srow = scores + row * 2048;
  unsigned* bins = binsAll[wave];

  unsigned k[32];
#pragma unroll
  for (int c = 0; c < 4; ++c) {
    float4 a = *(const float4*)(srow + c * 512 + lane * 8);
    float4 b = *(const float4*)(srow + c * 512 + lane * 8 + 4);
    k[c * 8 + 0] = fkey(a.x); k[c * 8 + 1] = fkey(a.y);
    k[c * 8 + 2] = fkey(a.z); k[c * 8 + 3] = fkey(a.w);
    k[c * 8 + 4] = fkey(b.x); k[c * 8 + 5] = fkey(b.y);
    k[c * 8 + 6] = fkey(b.z); k[c * 8 + 7] = fkey(b.w);
  }

  // row max (for softmax shift m = max(max_score, 0))
  unsigned kmax = 0;
#pragma unroll
  for (int i = 0; i < 32; ++i) kmax = max(kmax, k[i]);
#pragma unroll
  for (int off = 1; off < 64; off <<= 1)
    kmax = max(kmax, (unsigned)__shfl_xor((int)kmax, off));
  const float m = fmaxf(keyfloat(kmax), 0.f);

  // 4-pass radix select (MSB->LSB) for the KTOP-th largest key
  unsigned prefix = 0, mmask = 0, krem = KTOP;
  for (int shift = 24; shift >= 0; shift -= 8) {
    uint4 z; z.x = z.y = z.z = z.w = 0;
    *(uint4*)(bins + lane * 4) = z;
#pragma unroll
    for (int i = 0; i < 32; ++i)
      if ((k[i] & mmask) == prefix) atomicAdd(&bins[(k[i] >> shift) & 255], 1u);
    uint4 b = *(const uint4*)(bins + lane * 4);
    unsigned s = b.x + b.y + b.z + b.w;
    // inclusive suffix scan of s over lanes (sum over lanes >= this lane)
    unsigned t = s;
#pragma unroll
    for (int off = 1; off < 64; off <<= 1) {
      unsigned u = (unsigned)__shfl_down((int)t, off);
      t += (lane + off < 64) ? u : 0u;
    }
    const unsigned texcl = t - s;           // suffix over lanes > lane
    const unsigned c3 = texcl + b.w;        // count(digit >= lane*4+3)
    const unsigned c2 = c3 + b.z;
    const unsigned c1 = c2 + b.y;
    const unsigned c0 = c1 + b.x;
    unsigned pack = 0;                      // nonzero in exactly one lane
    if (c0 >= krem && c1 < krem)   pack = ((krem - c1) << 8) | (lane * 4 + 0);
    if (c1 >= krem && c2 < krem)   pack = ((krem - c2) << 8) | (lane * 4 + 1);
    if (c2 >= krem && c3 < krem)   pack = ((krem - c3) << 8) | (lane * 4 + 2);
    if (c3 >= krem && texcl < krem) pack = ((krem - texcl) << 8) | (lane * 4 + 3);
#pragma unroll
    for (int off = 1; off < 64; off <<= 1)
      pack |= (unsigned)__shfl_xor((int)pack, off);
    prefix |= (pack & 255u) << shift;
    krem = pack >> 8;                       // >=1 by construction
    mmask |= 0xFFu << shift;
  }
  const unsigned tkey = prefix;

  // tie-break: accept the krem lowest-index elements with key == tkey.
  // cut = global index of the last accepted tie.
  unsigned cut;
  {
    unsigned tiem = 0;
#pragma unroll
    for (int i = 0; i < 32; ++i)
      if (k[i] == tkey) tiem |= 1u << i;
    unsigned need = krem;
    for (;;) {
      unsigned myidx = 0xFFFFFFFFu;
      if (tiem) {
        int i = __ffs((int)tiem) - 1;       // lowest i = smallest global idx in lane
        myidx = ((unsigned)(i >> 3)) * 512u + (unsigned)lane * 8u + (unsigned)(i & 7);
      }
      unsigned minidx = myidx;
#pragma unroll
      for (int off = 1; off < 64; off <<= 1)
        minidx = min(minidx, (unsigned)__shfl_xor((int)minidx, off));
      if (--need == 0 || minidx == 0xFFFFFFFFu) { cut = minidx; break; }
      if (myidx == minidx) tiem &= tiem - 1; // consume in owning lane
    }
  }

  // weights: exp(s-m) if selected, exp(-m) otherwise; Z = sum of all weights
  const float eqw = __expf(keyfloat(tkey) - m);
  const float base = __expf(-m);
  float zsum = 0.f;
#pragma unroll
  for (int i = 0; i < 32; ++i) {
    const unsigned key = k[i];
    const unsigned idx = ((unsigned)(i >> 3)) * 512u + (unsigned)lane * 8u + (unsigned)(i & 7);
    float w;
    if (key > tkey) w = __expf(keyfloat(key) - m);
    else w = (key == tkey && idx <= cut) ? eqw : base;
    zsum += w;
    k[i] = __float_as_uint(w);              // stash unnormalized weight
  }
#pragma unroll
  for (int off = 1; off < 64; off <<= 1) zsum += __shfl_xor(zsum, off);
  const float invZ = 1.f / zsum;

  // attn row (bf16) reuses the front 4KB of this row's 8KB score slot
  unsigned short* arow = (unsigned short*)scores + row * 4096;
#pragma unroll
  for (int c = 0; c < 4; ++c) {
    union { unsigned short u[8]; int4 v4; } pk;
#pragma unroll
    for (int j = 0; j < 8; ++j)
      pk.u[j] = f2bf(__uint_as_float(k[c * 8 + j]) * invZ);
    *(int4*)(arow + c * 512 + lane * 8) = pk.v4;
  }
}

// ---------- launch ----------
// ws layout (bytes): Qb[0,16MB) Kb[16,32MB) VT[32,48MB) scores/attn[48,176MB)
extern "C" void kernel_launch(void* const* d_in, const int* in_sizes, int n_in,
                              void* d_out, int out_size, void* d_ws, size_t ws_size,
                              hipStream_t stream) {
  const float* Q = (const float*)d_in[0];
  const float* K = (const float*)d_in[1];
  const float* V = (const float*)d_in[2];
  float* out = (float*)d_out;
  char* ws = (char*)d_ws;
  unsigned short* Qb = (unsigned short*)(ws);
  unsigned short* Kb = (unsigned short*)(ws + ((size_t)16 << 20));
  unsigned short* VT = (unsigned short*)(ws + ((size_t)32 << 20));
  float* scores = (float*)(ws + ((size_t)48 << 20));

  const int nel = B_ * S_ * D_;  // 8388608
  cvt_qk<<<dim3(nel / 1024, 2), 256, 0, stream>>>(Q, K, Qb, Kb);
  transpose_v<<<dim3(D_ / 32, S_ / 32, B_), 256, 0, stream>>>(V, VT);
  // scores[b][q][k] = sum_d Q[q][d]*K[k][d] * scale ; score row pitch = 2048 f32
  gemm_qk<<<dim3(S_ / 128, S_ / 128, B_), 256, 0, stream>>>(
      Qb, D_, (long long)S_ * D_, Kb, D_, (long long)S_ * D_,
      scores, S_, (long long)S_ * S_, D_, QK_SCALE);
  topk_softmax<<<B_ * S_ / 4, 256, 0, stream>>>(scores);
  // out[b][q][d] = sum_k attn[q][k]*VT[d][k] ; attn row pitch = 4096 bf16 (8KB slots)
  gemm_pv<<<dim3(D_ / 128, S_ / 128, B_), 256, 0, stream>>>(
      (const unsigned short*)scores, 4096, (long long)S_ * 4096,
      VT, S_, (long long)D_ * S_, out, D_, (long long)S_ * D_, S_, 1.0f);
}